// Round 8
// baseline (217.014 us; speedup 1.0000x reference)
//
#include <hip/hip_runtime.h>
#include <math.h>

#define N_NODES 20000
#define N_EDGES 320000
#define IN_CH   256
#define HID_CH  256
#define OUT_CH  128
#define CAP     64     // per-node slot capacity; P(deg>64)~1e-15 for 320k->20k uniform
#define GK      256

#define NEB      142   // edge-pass blocks co-scheduled inside gemm1's dispatch
#define G1_TILES 626   // 313 row-tiles x 2 col-strips (TN=128)

typedef __attribute__((ext_vector_type(4))) unsigned short ushort4v;
typedef __attribute__((ext_vector_type(4))) float floatx4;
typedef __attribute__((ext_vector_type(2))) float floatx2;
typedef __attribute__((ext_vector_type(2))) _Float16 half2v;
typedef __attribute__((ext_vector_type(8))) _Float16 half8;

// ---------------------------------------------------------------------------
// prep0: zero deg + W^T fp16 planes. Replaces the hipMemsetAsync dispatch and
// must precede gemm1's dispatch (edge blocks atomically bump deg there).
// ---------------------------------------------------------------------------
__global__ __launch_bounds__(256)
void prep0_kernel(const float* __restrict__ W1, const float* __restrict__ W2,
                  _Float16* __restrict__ W1t, _Float16* __restrict__ W2t,
                  int* __restrict__ deg) {
    const int g = blockIdx.x * blockDim.x + threadIdx.x;
    const int gsz = gridDim.x * blockDim.x;
    for (int i = g; i < N_NODES; i += gsz) deg[i] = 0;
    // W1^T fp16 plane (K-contiguous lines)
    for (int t = g; t < (IN_CH * HID_CH) / 16; t += gsz) {
        int n = t >> 4;
        int kc = (t & 15) * 16;
        half8 h0, h1;
#pragma unroll
        for (int j = 0; j < 8; ++j) {
            h0[j] = (_Float16)W1[(size_t)(kc + j) * HID_CH + n];
            h1[j] = (_Float16)W1[(size_t)(kc + 8 + j) * HID_CH + n];
        }
        *(half8*)(W1t + (size_t)n * IN_CH + kc)     = h0;
        *(half8*)(W1t + (size_t)n * IN_CH + kc + 8) = h1;
    }
    // W2^T fp16 plane
    for (int t = g; t < (HID_CH * OUT_CH) / 16; t += gsz) {
        int n = t >> 4;
        int kc = (t & 15) * 16;
        half8 h0, h1;
#pragma unroll
        for (int j = 0; j < 8; ++j) {
            h0[j] = (_Float16)W2[(size_t)(kc + j) * OUT_CH + n];
            h1[j] = (_Float16)W2[(size_t)(kc + 8 + j) * OUT_CH + n];
        }
        *(half8*)(W2t + (size_t)n * HID_CH + kc)     = h0;
        *(half8*)(W2t + (size_t)n * HID_CH + kc + 8) = h1;
    }
}

// ---------------------------------------------------------------------------
// fp16 MFMA GEMM tile body (shared by gemm1 branch and gemm2 kernel).
// 64 x TN tile, BK=32, 4 waves (2x2), single mfma_f32_16x16x32_f16 per
// fragment, fp32 accum. Stores RAW fp16 -- dinv scaling applied in gathers
// (this is what makes the in-dispatch edge pass race-free).
// AMODE 1: A fp32, cvt in staging. AMODE 2: A fp16, pure-copy staging.
// ---------------------------------------------------------------------------
template <int AMODE, int TN>
static __device__ __forceinline__ void gemm_tile(
    const float* __restrict__ Afp, const _Float16* __restrict__ Ah,
    const _Float16* __restrict__ Bt, _Float16* __restrict__ C,
    int M, int N, int m0, int n0,
    _Float16 (&As)[64][36], _Float16 (&Bs)[TN][36])
{
    constexpr int NJ = TN / 32;
    const int tid = threadIdx.x;
    const int lane = tid & 63;
    const int wave = tid >> 6;
    const int wr = (wave >> 1) * 32;
    const int wc = (wave & 1) * (TN / 2);
    const int lm = lane & 15;
    const int lk = (lane >> 4) * 8;

    floatx4 acc[2][NJ];
#pragma unroll
    for (int i = 0; i < 2; ++i)
#pragma unroll
        for (int j = 0; j < NJ; ++j) acc[i][j] = (floatx4){0.f, 0.f, 0.f, 0.f};

    const int ar  = tid >> 2;          // 0..63 : A row within tile
    const int ako = (tid & 3) * 8;     // k sub-chunk

    for (int k0 = 0; k0 < GK; k0 += 32) {
        {   // A staging: 64 rows x 32 k
            half8 va = {};
            if (m0 + ar < M) {
                if (AMODE == 1) {
                    const float* ap = Afp + (size_t)(m0 + ar) * GK + k0 + ako;
                    float4 f0 = *(const float4*)ap;
                    float4 f1 = *(const float4*)(ap + 4);
                    va[0] = (_Float16)f0.x; va[1] = (_Float16)f0.y;
                    va[2] = (_Float16)f0.z; va[3] = (_Float16)f0.w;
                    va[4] = (_Float16)f1.x; va[5] = (_Float16)f1.y;
                    va[6] = (_Float16)f1.z; va[7] = (_Float16)f1.w;
                } else {
                    va = *(const half8*)(Ah + (size_t)(m0 + ar) * GK + k0 + ako);
                }
            }
            *(half8*)&As[ar][ako] = va;
        }
#pragma unroll
        for (int c = 0; c < TN / 64; ++c) {  // B staging: TN rows x 32 k, pure copy
            int ch = tid + c * 256;
            int r  = ch >> 2;
            int ko = (ch & 3) * 8;
            *(half8*)&Bs[r][ko] = *(const half8*)(Bt + (size_t)(n0 + r) * GK + k0 + ko);
        }
        __syncthreads();

        half8 ah[2];
#pragma unroll
        for (int i = 0; i < 2; ++i)
            ah[i] = *(const half8*)&As[wr + i * 16 + lm][lk];
#pragma unroll
        for (int j = 0; j < NJ; ++j) {
            half8 bh = *(const half8*)&Bs[wc + j * 16 + lm][lk];
#pragma unroll
            for (int i = 0; i < 2; ++i)
                acc[i][j] = __builtin_amdgcn_mfma_f32_16x16x32_f16(ah[i], bh, acc[i][j], 0, 0, 0);
        }
        __syncthreads();
    }

#pragma unroll
    for (int i = 0; i < 2; ++i) {
#pragma unroll
        for (int r = 0; r < 4; ++r) {
            int rowi = m0 + wr + i * 16 + (lane >> 4) * 4 + r;
            if (rowi < M) {
#pragma unroll
                for (int j = 0; j < NJ; ++j) {
                    C[(size_t)rowi * N + n0 + wc + j * 16 + lm] = (_Float16)acc[i][j][r];
                }
            }
        }
    }
}

// ---------------------------------------------------------------------------
// gemm1 dispatch: 142 edge-pass blocks + 626 gemm tile blocks. The edge CSR
// fill runs concurrently with (and hides under) gemm1; race-free because no
// gemm block reads deg/srcs (dinv moved to the gathers) and gather1 is a
// later dispatch. Edge blocks first so they start earliest.
// ---------------------------------------------------------------------------
__global__ __launch_bounds__(256, 2)
void gemm1_edge_kernel(const float* __restrict__ doc, const _Float16* __restrict__ W1t,
                       const int* __restrict__ row, const int* __restrict__ col,
                       int* __restrict__ deg, unsigned short* __restrict__ srcs,
                       _Float16* __restrict__ X1s) {
    __shared__ _Float16 As[64][36];
    __shared__ _Float16 Bs[128][36];
    const int bid = blockIdx.x;
    if (bid < NEB) {
        for (int i = bid * 256 + threadIdx.x; i < N_EDGES; i += NEB * 256) {
            int c = col[i];
            int r = row[i];
            int p = atomicAdd(&deg[c], 1);
            srcs[(size_t)c * CAP + p] = (unsigned short)r;
        }
    } else {
        int t = bid - NEB;                       // 0..625
        gemm_tile<1, 128>(doc, nullptr, W1t, X1s, N_NODES, HID_CH,
                          (t >> 1) * 64, (t & 1) * 128, As, Bs);
    }
}

__global__ __launch_bounds__(256, 2)
void gemm2_kernel(const _Float16* __restrict__ H1, const _Float16* __restrict__ W2t,
                  _Float16* __restrict__ X2s) {
    __shared__ _Float16 As[64][36];
    __shared__ _Float16 Bs[128][36];
    gemm_tile<2, 128>(nullptr, H1, W2t, X2s, N_NODES, OUT_CH,
                      blockIdx.x * 64, 0, As, Bs);
}

// ---------------------------------------------------------------------------
// XCD-sliced gather over ushort slot-CSR, fp16 X table (RAW, unscaled).
// Slice = 32 ch; 16 lanes per node (half2/lane) -> 4 node-groups/wave.
// Per-edge weight w = rsqrt(deg[src]+1): deg is an 80 KB L2-resident table,
// same address across the 16-lane node group -> broadcast load; rsqrt on the
// TRANS pipe hides under the gather's L2 latency.
// MODE 0: fp32 NT store to final out. MODE 1: relu + fp16 H1 (cached).
// ---------------------------------------------------------------------------
template <int C, int NSLICE, int MODE>
__global__ __launch_bounds__(256)
void gather_sliced_kernel(const _Float16* __restrict__ X, const int* __restrict__ deg,
                          const unsigned short* __restrict__ srcs,
                          const float* __restrict__ bias, float* __restrict__ outf,
                          _Float16* __restrict__ outh, int n) {
    constexpr int SW = C / NSLICE;
    static_assert(SW == 32, "slice must be 32 channels");
    const int slice = blockIdx.x % NSLICE;
    const int ngrp  = blockIdx.x / NSLICE;
    const int wave = threadIdx.x >> 6;
    const int lane = threadIdx.x & 63;
    const int g  = lane >> 4;          // node sub-group 0..3
    const int sl = lane & 15;          // sublane: 2 channels each
    const int node = ngrp * 16 + wave * 4 + g;
    if (node >= n) return;
    const int choff = slice * SW + sl * 2;
    const size_t beg = (size_t)node * CAP;
    const int cnt = deg[node];

    float a0 = 0.f, a1 = 0.f;
    int e = 0;
    for (; e + 4 <= cnt; e += 4) {
        ushort4v s4 = *(const ushort4v*)(srcs + beg + e);
        float w0 = 1.0f / sqrtf((float)(deg[s4.x] + 1));
        float w1 = 1.0f / sqrtf((float)(deg[s4.y] + 1));
        float w2 = 1.0f / sqrtf((float)(deg[s4.z] + 1));
        float w3 = 1.0f / sqrtf((float)(deg[s4.w] + 1));
        half2v v0 = *(const half2v*)(X + (size_t)s4.x * C + choff);
        half2v v1 = *(const half2v*)(X + (size_t)s4.y * C + choff);
        half2v v2 = *(const half2v*)(X + (size_t)s4.z * C + choff);
        half2v v3 = *(const half2v*)(X + (size_t)s4.w * C + choff);
        a0 += w0 * (float)v0.x + w1 * (float)v1.x + w2 * (float)v2.x + w3 * (float)v3.x;
        a1 += w0 * (float)v0.y + w1 * (float)v1.y + w2 * (float)v2.y + w3 * (float)v3.y;
    }
    for (; e < cnt; ++e) {
        int r = srcs[beg + e];
        float w = 1.0f / sqrtf((float)(deg[r] + 1));
        half2v v = *(const half2v*)(X + (size_t)r * C + choff);
        a0 += w * (float)v.x; a1 += w * (float)v.y;
    }

    const float dc = 1.0f / sqrtf((float)(cnt + 1));
    half2v vsh = *(const half2v*)(X + (size_t)node * C + choff);  // RAW self row
    float2 bb = *(const float2*)(bias + choff);

    float o0 = dc * (a0 + dc * (float)vsh.x) + bb.x;   // self weight: dc*dc
    float o1 = dc * (a1 + dc * (float)vsh.y) + bb.y;

    if constexpr (MODE == 1) {
        half2v h;
        h.x = (_Float16)fmaxf(o0, 0.f);
        h.y = (_Float16)fmaxf(o1, 0.f);
        *(half2v*)(outh + (size_t)node * C + choff) = h;   // cached: gemm2 reads next
    } else {
        floatx2 o = {o0, o1};
        __builtin_nontemporal_store(o, (floatx2*)(outf + (size_t)node * C + choff));
    }
}

// ---------------------------------------------------------------------------
extern "C" void kernel_launch(void* const* d_in, const int* in_sizes, int n_in,
                              void* d_out, int out_size, void* d_ws, size_t ws_size,
                              hipStream_t stream) {
    const float* doc_embeds = (const float*)d_in[0];   // [20000,256]
    const int*   edge_index = (const int*)d_in[1];     // [2,320000]
    const float* W1 = (const float*)d_in[2];           // [256,256]
    const float* b1 = (const float*)d_in[3];           // [256]
    const float* W2 = (const float*)d_in[4];           // [256,128]
    const float* b2 = (const float*)d_in[5];           // [128]
    float* out = (float*)d_out;                        // [20000,128]

    const int* row = edge_index;            // sources
    const int* col = edge_index + N_EDGES;  // destinations

    // ---------------- workspace layout (256B aligned) ----------------
    char* ws = (char*)d_ws;
    auto align_up = [](size_t x) { return (x + 255) / 256 * 256; };

    _Float16* X1s = (_Float16*)(ws);                              // gemm1 out fp16 (10.24 MB)
    _Float16* H1  = (_Float16*)(ws + align_up((size_t)N_NODES * HID_CH * 2));  // fp16 (10.24 MB)
    _Float16* X2s = X1s;                                          // gemm2 out reuses X1s (5.12 MB)
    char* meta = (char*)(ws + 2 * align_up((size_t)N_NODES * HID_CH * 2));
    _Float16* W1t = (_Float16*)(meta); meta += align_up((size_t)IN_CH * HID_CH * 2);
    _Float16* W2t = (_Float16*)(meta); meta += align_up((size_t)HID_CH * OUT_CH * 2);
    int*            deg  = (int*)(meta);            meta += align_up((size_t)N_NODES * 4);
    unsigned short* srcs = (unsigned short*)(meta); // 20000*64*2 = 2.56 MB

    // ---------------- prep0: deg zero + weight transpose (replaces memset) ----------------
    prep0_kernel<<<256, 256, 0, stream>>>(W1, W2, W1t, W2t, deg);

    // ---------------- layer 1: gemm1 || edge CSR fill (one dispatch) ----------------
    gemm1_edge_kernel<<<NEB + G1_TILES, 256, 0, stream>>>(
        doc_embeds, W1t, row, col, deg, srcs, X1s);

    gather_sliced_kernel<HID_CH, 8, 1><<<((N_NODES + 15) / 16) * 8, 256, 0, stream>>>(
        X1s, deg, srcs, b1, nullptr, H1, N_NODES);

    // ---------------- layer 2 ----------------
    gemm2_kernel<<<(N_NODES + 63) / 64, 256, 0, stream>>>(H1, W2t, X2s);

    gather_sliced_kernel<OUT_CH, 4, 0><<<((N_NODES + 15) / 16) * 4, 256, 0, stream>>>(
        X2s, deg, srcs, b2, out, nullptr, N_NODES);
}

// Round 9
// 165.340 us; speedup vs baseline: 1.3125x; 1.3125x over previous
//
#include <hip/hip_runtime.h>
#include <math.h>

#define N_NODES 20000
#define N_EDGES 320000
#define IN_CH   256
#define HID_CH  256
#define OUT_CH  128
#define CAP     64     // per-node slot capacity; P(deg>64)~1e-15 for 320k->20k uniform
#define GK      256

typedef __attribute__((ext_vector_type(8))) unsigned short ushort8;
typedef __attribute__((ext_vector_type(4))) unsigned short ushort4v;
typedef __attribute__((ext_vector_type(4))) float floatx4;
typedef __attribute__((ext_vector_type(2))) float floatx2;
typedef __attribute__((ext_vector_type(2))) _Float16 half2v;
typedef __attribute__((ext_vector_type(8))) _Float16 half8;

// ---------------------------------------------------------------------------
// fused prep: W^T fp16 planes + slot-CSR degfill. deg must be zeroed
// beforehand (hipMemsetAsync). (round-7 verbatim)
// ---------------------------------------------------------------------------
__global__ __launch_bounds__(256)
void prep_kernel(const float* __restrict__ W1, const float* __restrict__ W2,
                 _Float16* __restrict__ W1t, _Float16* __restrict__ W2t,
                 const int* __restrict__ row, const int* __restrict__ col,
                 int* __restrict__ deg, unsigned short* __restrict__ srcs) {
    const int g = blockIdx.x * blockDim.x + threadIdx.x;
    const int gsz = gridDim.x * blockDim.x;
    // W1^T fp16 plane (K-contiguous lines)
    for (int t = g; t < (IN_CH * HID_CH) / 16; t += gsz) {
        int n = t >> 4;
        int kc = (t & 15) * 16;
        half8 h0, h1;
#pragma unroll
        for (int j = 0; j < 8; ++j) {
            h0[j] = (_Float16)W1[(size_t)(kc + j) * HID_CH + n];
            h1[j] = (_Float16)W1[(size_t)(kc + 8 + j) * HID_CH + n];
        }
        *(half8*)(W1t + (size_t)n * IN_CH + kc)     = h0;
        *(half8*)(W1t + (size_t)n * IN_CH + kc + 8) = h1;
    }
    // W2^T fp16 plane
    for (int t = g; t < (HID_CH * OUT_CH) / 16; t += gsz) {
        int n = t >> 4;
        int kc = (t & 15) * 16;
        half8 h0, h1;
#pragma unroll
        for (int j = 0; j < 8; ++j) {
            h0[j] = (_Float16)W2[(size_t)(kc + j) * OUT_CH + n];
            h1[j] = (_Float16)W2[(size_t)(kc + 8 + j) * OUT_CH + n];
        }
        *(half8*)(W2t + (size_t)n * HID_CH + kc)     = h0;
        *(half8*)(W2t + (size_t)n * HID_CH + kc + 8) = h1;
    }
    // slot-CSR build: deg count + bucket fill (no scan)
    for (int i = g; i < N_EDGES; i += gsz) {
        int c = col[i];
        int r = row[i];
        int p = atomicAdd(&deg[c], 1);
        srcs[(size_t)c * CAP + p] = (unsigned short)r;
    }
}

// ---------------------------------------------------------------------------
// fp16 MFMA GEMM (single mfma_f32_16x16x32_f16 per fragment, fp32 accum).
// 64 x TN tile, BK=32, 4 waves (2x2). Epilogue scales row by rsqrt(deg+1)
// -- computed ONCE per row here; this factorization is load-bearing (round-8
// A/B: per-edge dinv in the gather = 128x redundant rsqrt, +50 µs).
// AMODE 1: A fp32 cvt in staging. AMODE 2: A fp16 pure-copy staging.
// (round-7 verbatim)
// ---------------------------------------------------------------------------
template <int AMODE, int TN>
__global__ __launch_bounds__(256, 2)
void gemm_mfma_kernel(const float* __restrict__ Afp, const _Float16* __restrict__ Ah,
                      const _Float16* __restrict__ Bt,
                      const int* __restrict__ deg, _Float16* __restrict__ C, int M, int N) {
    constexpr int NJ = TN / 32;          // 16-col MFMA tiles per wave
    __shared__ _Float16 As[64][36];
    __shared__ _Float16 Bs[TN][36];
    const int tid = threadIdx.x;
    const int m0 = blockIdx.y * 64;
    const int n0 = blockIdx.x * TN;
    const int lane = tid & 63;
    const int wave = tid >> 6;
    const int wr = (wave >> 1) * 32;
    const int wc = (wave & 1) * (TN / 2);
    const int lm = lane & 15;
    const int lk = (lane >> 4) * 8;

    floatx4 acc[2][NJ];
#pragma unroll
    for (int i = 0; i < 2; ++i)
#pragma unroll
        for (int j = 0; j < NJ; ++j) acc[i][j] = (floatx4){0.f, 0.f, 0.f, 0.f};

    const int ar  = tid >> 2;          // 0..63 : A row within tile
    const int ako = (tid & 3) * 8;     // k sub-chunk

    for (int k0 = 0; k0 < GK; k0 += 32) {
        {   // A staging: 64 rows x 32 k
            half8 va = {};
            if (m0 + ar < M) {
                if (AMODE == 1) {
                    const float* ap = Afp + (size_t)(m0 + ar) * GK + k0 + ako;
                    float4 f0 = *(const float4*)ap;
                    float4 f1 = *(const float4*)(ap + 4);
                    va[0] = (_Float16)f0.x; va[1] = (_Float16)f0.y;
                    va[2] = (_Float16)f0.z; va[3] = (_Float16)f0.w;
                    va[4] = (_Float16)f1.x; va[5] = (_Float16)f1.y;
                    va[6] = (_Float16)f1.z; va[7] = (_Float16)f1.w;
                } else {
                    va = *(const half8*)(Ah + (size_t)(m0 + ar) * GK + k0 + ako);
                }
            }
            *(half8*)&As[ar][ako] = va;
        }
#pragma unroll
        for (int c = 0; c < TN / 64; ++c) {  // B staging: TN rows x 32 k, pure copy
            int ch = tid + c * 256;
            int r  = ch >> 2;
            int ko = (ch & 3) * 8;
            *(half8*)&Bs[r][ko] = *(const half8*)(Bt + (size_t)(n0 + r) * GK + k0 + ko);
        }
        __syncthreads();

        half8 ah[2];
#pragma unroll
        for (int i = 0; i < 2; ++i)
            ah[i] = *(const half8*)&As[wr + i * 16 + lm][lk];
#pragma unroll
        for (int j = 0; j < NJ; ++j) {
            half8 bh = *(const half8*)&Bs[wc + j * 16 + lm][lk];
#pragma unroll
            for (int i = 0; i < 2; ++i)
                acc[i][j] = __builtin_amdgcn_mfma_f32_16x16x32_f16(ah[i], bh, acc[i][j], 0, 0, 0);
        }
        __syncthreads();
    }

#pragma unroll
    for (int i = 0; i < 2; ++i) {
#pragma unroll
        for (int r = 0; r < 4; ++r) {
            int rowi = m0 + wr + i * 16 + (lane >> 4) * 4 + r;
            if (rowi < M) {
                float dr = 1.0f / sqrtf((float)(deg[rowi] + 1));
#pragma unroll
                for (int j = 0; j < NJ; ++j) {
                    C[(size_t)rowi * N + n0 + wc + j * 16 + lm] = (_Float16)(dr * acc[i][j][r]);
                }
            }
        }
    }
}

// ---------------------------------------------------------------------------
// XCD-sliced gather over ushort slot-CSR, fp16 X table (dinv-prescaled rows).
// Slice = 32 ch; 16 lanes per node (half2/lane) -> 4 node-groups/wave.
// CHANGE vs round 7: edge loop unrolled 8-wide -- one 16B ushort8 index load,
// all 8 X-row loads issued before accumulation (gather is latency-bound on
// the srcs->X chain: round-8 counters showed 64% occupancy, HBM 6%).
// MODE 0: fp32 NT store to final out. MODE 1: relu + fp16 H1 (cached).
// ---------------------------------------------------------------------------
template <int C, int NSLICE, int MODE>
__global__ __launch_bounds__(256)
void gather_sliced_kernel(const _Float16* __restrict__ X, const int* __restrict__ deg,
                          const unsigned short* __restrict__ srcs,
                          const float* __restrict__ bias, float* __restrict__ outf,
                          _Float16* __restrict__ outh, int n) {
    constexpr int SW = C / NSLICE;
    static_assert(SW == 32, "slice must be 32 channels");
    const int slice = blockIdx.x % NSLICE;
    const int ngrp  = blockIdx.x / NSLICE;
    const int wave = threadIdx.x >> 6;
    const int lane = threadIdx.x & 63;
    const int g  = lane >> 4;          // node sub-group 0..3
    const int sl = lane & 15;          // sublane: 2 channels each
    const int node = ngrp * 16 + wave * 4 + g;
    if (node >= n) return;
    const int choff = slice * SW + sl * 2;
    const size_t beg = (size_t)node * CAP;
    const int cnt = deg[node];

    float a0 = 0.f, a1 = 0.f;
    int e = 0;
    for (; e + 8 <= cnt; e += 8) {             // 8-wide: one 16B index load,
        ushort8 s8 = *(const ushort8*)(srcs + beg + e);   // 8 X loads in flight
        half2v v0 = *(const half2v*)(X + (size_t)s8[0] * C + choff);
        half2v v1 = *(const half2v*)(X + (size_t)s8[1] * C + choff);
        half2v v2 = *(const half2v*)(X + (size_t)s8[2] * C + choff);
        half2v v3 = *(const half2v*)(X + (size_t)s8[3] * C + choff);
        half2v v4 = *(const half2v*)(X + (size_t)s8[4] * C + choff);
        half2v v5 = *(const half2v*)(X + (size_t)s8[5] * C + choff);
        half2v v6 = *(const half2v*)(X + (size_t)s8[6] * C + choff);
        half2v v7 = *(const half2v*)(X + (size_t)s8[7] * C + choff);
        a0 += (float)v0.x + (float)v1.x + (float)v2.x + (float)v3.x
            + (float)v4.x + (float)v5.x + (float)v6.x + (float)v7.x;
        a1 += (float)v0.y + (float)v1.y + (float)v2.y + (float)v3.y
            + (float)v4.y + (float)v5.y + (float)v6.y + (float)v7.y;
    }
    for (; e + 4 <= cnt; e += 4) {
        ushort4v s4 = *(const ushort4v*)(srcs + beg + e);
        half2v v0 = *(const half2v*)(X + (size_t)s4.x * C + choff);
        half2v v1 = *(const half2v*)(X + (size_t)s4.y * C + choff);
        half2v v2 = *(const half2v*)(X + (size_t)s4.z * C + choff);
        half2v v3 = *(const half2v*)(X + (size_t)s4.w * C + choff);
        a0 += (float)v0.x + (float)v1.x + (float)v2.x + (float)v3.x;
        a1 += (float)v0.y + (float)v1.y + (float)v2.y + (float)v3.y;
    }
    for (; e < cnt; ++e) {
        int r = srcs[beg + e];
        half2v v = *(const half2v*)(X + (size_t)r * C + choff);
        a0 += (float)v.x; a1 += (float)v.y;
    }

    const float dc = 1.0f / sqrtf((float)(cnt + 1));
    half2v vsh = *(const half2v*)(X + (size_t)node * C + choff);  // dinv-prescaled
    float2 bb = *(const float2*)(bias + choff);

    float o0 = dc * (a0 + (float)vsh.x) + bb.x;
    float o1 = dc * (a1 + (float)vsh.y) + bb.y;

    if constexpr (MODE == 1) {
        half2v h;
        h.x = (_Float16)fmaxf(o0, 0.f);
        h.y = (_Float16)fmaxf(o1, 0.f);
        *(half2v*)(outh + (size_t)node * C + choff) = h;   // cached: gemm2 reads next
    } else {
        floatx2 o = {o0, o1};
        __builtin_nontemporal_store(o, (floatx2*)(outf + (size_t)node * C + choff));
    }
}

// ---------------------------------------------------------------------------
extern "C" void kernel_launch(void* const* d_in, const int* in_sizes, int n_in,
                              void* d_out, int out_size, void* d_ws, size_t ws_size,
                              hipStream_t stream) {
    const float* doc_embeds = (const float*)d_in[0];   // [20000,256]
    const int*   edge_index = (const int*)d_in[1];     // [2,320000]
    const float* W1 = (const float*)d_in[2];           // [256,256]
    const float* b1 = (const float*)d_in[3];           // [256]
    const float* W2 = (const float*)d_in[4];           // [256,128]
    const float* b2 = (const float*)d_in[5];           // [128]
    float* out = (float*)d_out;                        // [20000,128]

    const int* row = edge_index;            // sources
    const int* col = edge_index + N_EDGES;  // destinations

    // ---------------- workspace layout (256B aligned) ----------------
    char* ws = (char*)d_ws;
    auto align_up = [](size_t x) { return (x + 255) / 256 * 256; };

    _Float16* X1s = (_Float16*)(ws);                              // gemm1 out fp16 (10.24 MB)
    _Float16* H1  = (_Float16*)(ws + align_up((size_t)N_NODES * HID_CH * 2));  // fp16 (10.24 MB)
    _Float16* X2s = X1s;                                          // gemm2 out reuses X1s (5.12 MB)
    char* meta = (char*)(ws + 2 * align_up((size_t)N_NODES * HID_CH * 2));
    _Float16* W1t = (_Float16*)(meta); meta += align_up((size_t)IN_CH * HID_CH * 2);
    _Float16* W2t = (_Float16*)(meta); meta += align_up((size_t)HID_CH * OUT_CH * 2);
    int*            deg  = (int*)(meta);            meta += align_up((size_t)N_NODES * 4);
    unsigned short* srcs = (unsigned short*)(meta); // 20000*64*2 = 2.56 MB

    // ---------------- prep: zero deg (memset), fused weights + slot-CSR ----------------
    hipMemsetAsync(deg, 0, (size_t)N_NODES * 4, stream);
    prep_kernel<<<(N_EDGES + 255) / 256, 256, 0, stream>>>(
        W1, W2, W1t, W2t, row, col, deg, srcs);

    // ---------------- layer 1 ----------------
    {
        dim3 grid(HID_CH / 128, (N_NODES + 63) / 64);   // (2, 313) = 626 blocks
        gemm_mfma_kernel<1, 128><<<grid, 256, 0, stream>>>(
            doc_embeds, nullptr, W1t, deg, X1s, N_NODES, HID_CH);
    }
    gather_sliced_kernel<HID_CH, 8, 1><<<((N_NODES + 15) / 16) * 8, 256, 0, stream>>>(
        X1s, deg, srcs, b1, nullptr, H1, N_NODES);

    // ---------------- layer 2 ----------------
    {
        dim3 grid(OUT_CH / 128, (N_NODES + 63) / 64);   // (1, 313) = 313 blocks
        gemm_mfma_kernel<2, 128><<<grid, 256, 0, stream>>>(
            nullptr, H1, W2t, deg, X2s, N_NODES, OUT_CH);
    }
    gather_sliced_kernel<OUT_CH, 4, 0><<<((N_NODES + 15) / 16) * 4, 256, 0, stream>>>(
        X2s, deg, srcs, b2, out, nullptr, N_NODES);
}